// Round 4
// baseline (312.588 us; speedup 1.0000x reference)
//
#include <hip/hip_runtime.h>
#include <math.h>

// Swin window attention, WS=8, HEADS=3, C=48, hd=16. fp16 MFMA everywhere.
// R3: TWO windows per block (512 thr / 8 waves). Horizontally-adjacent windows
// share memory transactions: phase-1 loads and phase-4 stores are 64-B
// segments (16 consecutive floats). Attention = R0's proven 3-wave structure
// per window (waves 0-2: win0 heads, 4-6: win1 heads). Block count halved.
// launch_bounds(512,6): VGPR cap 85 (R2b's cap-64 collapsed ILP to 32 VGPR).
// no-max exp2 softmax (validated R1/R2b), bias pre-scaled by log2e in prep.

typedef _Float16 f16x4 __attribute__((ext_vector_type(4)));
typedef float    f32x4 __attribute__((ext_vector_type(4)));

#define LOG2E 1.44269504f

// d_ws layout (bytes)
#define WS_BFRAG 0        // bias frags (pre-scaled by log2e): 3*16*64*16B = 49152
#define WS_WFRAG 49152    // qkv W frags: 27 x 64 x f16x4 = 13824
#define WS_PFRAG 62976    // proj W frags: 9 x 64 x f16x4 = 4608
#define WS_QKVB  67584    // 144 f32
#define WS_PBIAS 68160    // 48 f32

// LDS strides (halves)
#define XT_S 52   // X/O token rows [128][52]
#define T_S  100  // QK token rows  [128][100] (Q cols 0..47, K 48..95)
#define VD_S 68   // V d-major      [2][48][68]

// ---------------- prep: bias MLP + weight/bias fragment packing -------------
__global__ __launch_bounds__(256) void prep_kernel(
    const float* __restrict__ m1w, const float* __restrict__ m1b,
    const float* __restrict__ m2w, const float* __restrict__ m2b,
    const float* __restrict__ qk_w, const float* __restrict__ v_w,
    const float* __restrict__ proj_w,
    const float* __restrict__ qk_b, const float* __restrict__ v_b,
    const float* __restrict__ proj_b,
    unsigned char* __restrict__ ws)
{
    __shared__ float sm[1536];   // m1w[512] | m1b[256] | m2w[768]

    float*     bfrag = (float*)(ws + WS_BFRAG);
    _Float16*  wfrag = (_Float16*)(ws + WS_WFRAG);
    _Float16*  pfrag = (_Float16*)(ws + WS_PFRAG);
    float*     qkvb  = (float*)(ws + WS_QKVB);
    float*     pbias = (float*)(ws + WS_PBIAS);

    const int gid = blockIdx.x * 256 + threadIdx.x;
    if (blockIdx.x < 16) {
        for (int i = threadIdx.x; i < 1536; i += 256) {
            float v;
            if (i < 512)      v = m1w[i];
            else if (i < 768) v = m1b[i - 512];
            else              v = m2w[i - 768];
            sm[i] = v;
        }
        __syncthreads();

        // bias MLP for (n, m); scatter into Sᵀ C-layout fragment order.
        const int n = gid >> 6, m = gid & 63;
        float di = (float)((n >> 3) - (m >> 3));
        float dj = (float)((n & 7) - (m & 7));
        float r0 = copysignf(log1pf(fabsf(di)), di);
        float r1 = copysignf(log1pf(fabsf(dj)), dj);
        float a0 = 0.f, a1 = 0.f, a2 = 0.f;
        #pragma unroll 4
        for (int k = 0; k < 256; ++k) {
            float hv = fmaxf(sm[512 + k] + sm[2*k]*r0 + sm[2*k+1]*r1, 0.f);
            a0 += sm[768 + k]  * hv;
            a1 += sm[1024 + k] * hv;
            a2 += sm[1280 + k] * hv;
        }
        const int tm = m >> 4, quad = (m >> 2) & 3, r = m & 3, tn = n >> 4;
        const int ln = quad*16 + (n & 15);
        const int base = ((tm*4 + tn)*64 + ln)*4 + r;
        bfrag[(0*16*64)*4  + base] = (a0 + m2b[0]) * LOG2E;
        bfrag[(16*64)*4    + base] = (a1 + m2b[1]) * LOG2E;
        bfrag[(32*64)*4    + base] = (a2 + m2b[2]) * LOG2E;
    } else if (gid < 4096 + 6912) {
        const int idx = gid - 4096;           // ((mt*3+ks)*64 + l)*4 + j
        const int j = idx & 3, l = (idx >> 2) & 63, f = idx >> 8;
        const int ks = f % 3, mt = f / 3;
        const int row = mt*16 + (l & 15), col = ks*16 + ((l >> 4) << 2) + j;
        const float wv = (row < 96) ? qk_w[row*48 + col] : v_w[(row-96)*48 + col];
        wfrag[idx] = (_Float16)wv;
    } else if (gid < 11008 + 2304) {
        const int idx = gid - 11008;
        const int j = idx & 3, l = (idx >> 2) & 63, f = idx >> 8;
        const int ks = f % 3, mt = f / 3;
        const int row = mt*16 + (l & 15), col = ks*16 + ((l >> 4) << 2) + j;
        pfrag[idx] = (_Float16)proj_w[row*48 + col];
    } else if (gid < 13312 + 144) {
        const int c = gid - 13312;
        qkvb[c] = (c < 96) ? qk_b[c] : v_b[c - 96];
    } else if (gid < 13456 + 48) {
        pbias[gid - 13456] = proj_b[gid - 13456];
    }
}

// ---------------- fused QKV + attention + proj, fp16 MFMA, 2 windows --------
__global__ __launch_bounds__(512, 6) void win_attn_kernel(
    const float* __restrict__ X, const unsigned char* __restrict__ ws,
    float* __restrict__ out, int nblk)
{
    __shared__ _Float16 smem[25984];           // 51968 B -> 3 blocks/CU
    _Float16* sA = smem;                       // [128][52]: X f16; later Oᵀ
    _Float16* sT = smem + 128*XT_S;            // [128][100]: Q 0..47, K 48..95
    _Float16* sV = smem + 128*XT_S + 128*T_S;  // [2][48][68]: V d-major

    const float* bfrag = (const float*)(ws + WS_BFRAG);
    const f16x4* wfrag = (const f16x4*)(ws + WS_WFRAG);
    const f16x4* pfrag = (const f16x4*)(ws + WS_PFRAG);
    const float* qkvb  = (const float*)(ws + WS_QKVB);
    const float* pbias = (const float*)(ws + WS_PBIAS);

    const int tid  = threadIdx.x;
    const int wv   = tid >> 6, lane = tid & 63;
    const int lq   = lane >> 4, lm = lane & 15;

    const int blk = blockIdx.x;
    const int wid = (blk & 7) * (nblk >> 3) + (blk >> 3);   // XCD swizzle
    const int batch = wid >> 11;                 // 64*32 = 2048 pairs/batch
    const int wh = (wid >> 5) & 63, wp = wid & 31;
    const int h0 = wh << 3, w0 = wp << 4;        // pair-window = 16 px wide

    const float* Xb = X + ((size_t)batch * 48 << 18);

    // ---- phase 1: stage pair-window X -> f16 token-major LDS ---------------
    // wave-instr = 4 rows x 16 consecutive floats = 4 x 64-B segments.
    {
        const int seg = lane >> 4, col = lane & 15;
        float xv[12];
        #pragma unroll
        for (int k = 0; k < 12; ++k) {
            const int c   = wv + ((k >> 1) << 3);
            const int row = ((k & 1) << 2) + seg;
            xv[k] = Xb[((size_t)c << 18) + (size_t)(h0 + row) * 512 + (w0 + col)];
        }
        #pragma unroll
        for (int k = 0; k < 12; ++k) {
            const int c    = wv + ((k >> 1) << 3);
            const int row  = ((k & 1) << 2) + seg;
            const int gtok = ((col >> 3) << 6) + (row << 3) + (col & 7);
            sA[gtok*XT_S + c] = (_Float16)xv[k];
        }
    }
    __syncthreads();

    // ---- phase 2: QKV GEMM [144x48]x[48x128]; wave w = gtoks 16w..16w+15 ---
    {
        f16x4 bx[3];
        #pragma unroll
        for (int ks = 0; ks < 3; ++ks)
            bx[ks] = *(const f16x4*)&sA[(wv*16 + lm)*XT_S + ks*16 + lq*4];

        const int gtok = wv*16 + lm;
        const int tok  = (wv & 3)*16 + lm;     // within-window token
        const int winb = (wv >> 2) * 48 * VD_S;
        #pragma unroll
        for (int mt = 0; mt < 9; ++mt) {
            f32x4 acc = *(const f32x4*)&qkvb[mt*16 + lq*4];
            #pragma unroll
            for (int ks = 0; ks < 3; ++ks)
                acc = __builtin_amdgcn_mfma_f32_16x16x16f16(
                          wfrag[(mt*3+ks)*64 + lane], bx[ks], acc, 0, 0, 0);
            if (mt < 3) {                      // Q: fold 1/sqrt(hd) * log2e
                f16x4 hv;
                #pragma unroll
                for (int r = 0; r < 4; ++r) hv[r] = (_Float16)(acc[r] * (0.25f*LOG2E));
                *(f16x4*)&sT[gtok*T_S + mt*16 + lq*4] = hv;
            } else if (mt < 6) {               // K -> cols 48..95
                f16x4 hv;
                #pragma unroll
                for (int r = 0; r < 4; ++r) hv[r] = (_Float16)acc[r];
                *(f16x4*)&sT[gtok*T_S + mt*16 + lq*4] = hv;
            } else {                           // V -> per-window d-major
                #pragma unroll
                for (int r = 0; r < 4; ++r)
                    sV[winb + ((mt-6)*16 + lq*4 + r)*VD_S + tok] = (_Float16)acc[r];
            }
        }
    }
    __syncthreads();

    // ---- phase 3: attention, R0 3-wave form per window ---------------------
    // waves 0-2: window 0 heads 0-2; waves 4-6: window 1; waves 3,7 idle.
    if ((wv & 3) < 3) {
        const int h = wv & 3, base = (wv >> 2) << 6;
        const int winb = (wv >> 2) * 48 * VD_S;
        f16x4 ak[4], bq[4];
        #pragma unroll
        for (int t = 0; t < 4; ++t) {
            ak[t] = *(const f16x4*)&sT[(base + t*16 + lm)*T_S + 48 + h*16 + lq*4];
            bq[t] = *(const f16x4*)&sT[(base + t*16 + lm)*T_S + h*16 + lq*4];
        }
        f32x4 s[4][4];                          // Sᵀ tiles [tm][tn], C = bias
        const f32x4* bf = (const f32x4*)bfrag + (size_t)h*16*64;
        #pragma unroll
        for (int tm = 0; tm < 4; ++tm)
            #pragma unroll
            for (int tn = 0; tn < 4; ++tn)
                s[tm][tn] = __builtin_amdgcn_mfma_f32_16x16x16f16(
                                ak[tm], bq[tn], bf[(tm*4 + tn)*64 + lane], 0, 0, 0);
        // softmax over m (rows of Sᵀ): no-max exp2 (bounded logits), rcp
        float rinv[4];
        #pragma unroll
        for (int tn = 0; tn < 4; ++tn) {
            float sum = 0.f;
            #pragma unroll
            for (int tm = 0; tm < 4; ++tm)
                #pragma unroll
                for (int r = 0; r < 4; ++r) {
                    float e = __builtin_amdgcn_exp2f(s[tm][tn][r]);
                    s[tm][tn][r] = e; sum += e;
                }
            sum += __shfl_xor(sum, 16);
            sum += __shfl_xor(sum, 32);
            rinv[tn] = __builtin_amdgcn_rcpf(sum);
        }
        // PV: Oᵀ = Vᵀ · Pᵀ ; Pᵀ C-regs are directly valid B-fragments
        f16x4 av[4];
        #pragma unroll
        for (int tm = 0; tm < 4; ++tm)
            av[tm] = *(const f16x4*)&sV[winb + (h*16 + lm)*VD_S + tm*16 + lq*4];
        #pragma unroll
        for (int tn = 0; tn < 4; ++tn) {
            f32x4 o = {0.f, 0.f, 0.f, 0.f};
            #pragma unroll
            for (int tm = 0; tm < 4; ++tm) {
                f16x4 pf;
                pf[0] = (_Float16)s[tm][tn][0];
                pf[1] = (_Float16)s[tm][tn][1];
                pf[2] = (_Float16)s[tm][tn][2];
                pf[3] = (_Float16)s[tm][tn][3];
                o = __builtin_amdgcn_mfma_f32_16x16x16f16(av[tm], pf, o, 0, 0, 0);
            }
            f16x4 hv;
            #pragma unroll
            for (int r = 0; r < 4; ++r) hv[r] = (_Float16)(o[r] * rinv[tn]);
            *(f16x4*)&sA[(base + tn*16 + lm)*XT_S + h*16 + lq*4] = hv;  // Oᵀ
        }
    }
    __syncthreads();

    // ---- phase 4: proj [48x48]x[48x128]; wave w = pixel-row h0+w -----------
    // M-tile = row w of BOTH windows (lm = win*8+col) -> stores are 16
    // consecutive floats = 64-B segments.
    {
        const int gt4 = ((lm >> 3) << 6) + (wv << 3) + (lm & 7);
        f16x4 bo[3];
        #pragma unroll
        for (int ks = 0; ks < 3; ++ks)
            bo[ks] = *(const f16x4*)&sA[gt4*XT_S + ks*16 + lq*4];

        float* ob = out + ((size_t)batch * 48 << 18);
        const size_t pixr = (size_t)(h0 + wv) * 512 + w0 + lm;
        #pragma unroll
        for (int mt = 0; mt < 3; ++mt) {
            f32x4 acc = *(const f32x4*)&pbias[mt*16 + lq*4];
            #pragma unroll
            for (int ks = 0; ks < 3; ++ks)
                acc = __builtin_amdgcn_mfma_f32_16x16x16f16(
                          pfrag[(mt*3+ks)*64 + lane], bo[ks], acc, 0, 0, 0);
            #pragma unroll
            for (int r = 0; r < 4; ++r)
                ob[((size_t)(mt*16 + lq*4 + r) << 18) + pixr] = acc[r];
        }
    }
}

extern "C" void kernel_launch(void* const* d_in, const int* in_sizes, int n_in,
                              void* d_out, int out_size, void* d_ws, size_t ws_size,
                              hipStream_t stream) {
    (void)n_in; (void)out_size; (void)ws_size;
    const float* X      = (const float*)d_in[0];
    const float* v_w    = (const float*)d_in[1];
    const float* v_b    = (const float*)d_in[2];
    const float* qk_w   = (const float*)d_in[3];
    const float* qk_b   = (const float*)d_in[4];
    const float* proj_w = (const float*)d_in[5];
    const float* proj_b = (const float*)d_in[6];
    const float* m1w    = (const float*)d_in[7];
    const float* m1b    = (const float*)d_in[8];
    const float* m2w    = (const float*)d_in[9];
    const float* m2b    = (const float*)d_in[10];
    float* out = (float*)d_out;
    unsigned char* ws = (unsigned char*)d_ws;   // ~68.4 KB used

    const int B = in_sizes[0] / (48 * 512 * 512);   // = 2
    const int nblk = B * 64 * 32;                   // window PAIRS

    hipLaunchKernelGGL(prep_kernel, dim3(53), dim3(256), 0, stream,
                       m1w, m1b, m2w, m2b, qk_w, v_w, proj_w, qk_b, v_b, proj_b, ws);
    hipLaunchKernelGGL(win_attn_kernel, dim3(nblk), dim3(512), 0, stream,
                       X, ws, out, nblk);
}

// Round 5
// 259.805 us; speedup vs baseline: 1.2032x; 1.2032x over previous
//
#include <hip/hip_runtime.h>
#include <math.h>

// Swin window attention, WS=8, HEADS=3, C=48, hd=16. fp16 MFMA everywhere.
// One 256-thread block per 8x8 window; Sᵀ-form QK so P feeds PV from registers.
// R4 = R0's proven structure (119us) with ONLY validated math substitutions:
// no-max softmax (bounded logits; absmax unchanged across 3 runs), exp2 with
// log2e pre-folded into Q-scale and bias table, rcp for 1/sum, LDS-staged
// prep MLP. Structure, barriers, staging, launch bounds: byte-identical to R0.

typedef _Float16 f16x4 __attribute__((ext_vector_type(4)));
typedef float    f32x4 __attribute__((ext_vector_type(4)));

#define LOG2E 1.44269504f

// d_ws layout (bytes)
#define WS_BFRAG 0        // bias frags (pre-scaled by log2e): 3*16*64*16B = 49152
#define WS_WFRAG 49152    // qkv W frags: 27 x 64 x f16x4 = 13824
#define WS_PFRAG 62976    // proj W frags: 9 x 64 x f16x4 = 4608
#define WS_QKVB  67584    // 144 f32
#define WS_PBIAS 68160    // 48 f32

// LDS strides (in halves; even-dword strides, 8B-aligned fragment reads)
#define XT_S 52   // X/O token rows [64][52]
#define T_S  100  // QK token rows  [64][100] (chans 0..95)
#define VD_S 68   // V d-major      [48][68]

// ---------------- prep: bias MLP + weight/bias fragment packing -------------
__global__ __launch_bounds__(256) void prep_kernel(
    const float* __restrict__ m1w, const float* __restrict__ m1b,
    const float* __restrict__ m2w, const float* __restrict__ m2b,
    const float* __restrict__ qk_w, const float* __restrict__ v_w,
    const float* __restrict__ proj_w,
    const float* __restrict__ qk_b, const float* __restrict__ v_b,
    const float* __restrict__ proj_b,
    unsigned char* __restrict__ ws)
{
    __shared__ float sm[1536];   // m1w[512] | m1b[256] | m2w[768]

    float*     bfrag = (float*)(ws + WS_BFRAG);
    _Float16*  wfrag = (_Float16*)(ws + WS_WFRAG);
    _Float16*  pfrag = (_Float16*)(ws + WS_PFRAG);
    float*     qkvb  = (float*)(ws + WS_QKVB);
    float*     pbias = (float*)(ws + WS_PBIAS);

    const int gid = blockIdx.x * 256 + threadIdx.x;
    if (blockIdx.x < 16) {
        // stage MLP params in LDS (global re-reads had no latency hiding at
        // only 16 resident blocks)
        for (int i = threadIdx.x; i < 1536; i += 256) {
            float v;
            if (i < 512)      v = m1w[i];
            else if (i < 768) v = m1b[i - 512];
            else              v = m2w[i - 768];
            sm[i] = v;
        }
        __syncthreads();

        // bias MLP for (n, m); scatter into Sᵀ C-layout fragment order.
        // Pre-scaled by log2e so phase-3 softmax uses raw exp2.
        const int n = gid >> 6, m = gid & 63;
        float di = (float)((n >> 3) - (m >> 3));
        float dj = (float)((n & 7) - (m & 7));
        float r0 = copysignf(log1pf(fabsf(di)), di);
        float r1 = copysignf(log1pf(fabsf(dj)), dj);
        float a0 = 0.f, a1 = 0.f, a2 = 0.f;
        #pragma unroll 4
        for (int k = 0; k < 256; ++k) {
            float hv = fmaxf(sm[512 + k] + sm[2*k]*r0 + sm[2*k+1]*r1, 0.f);
            a0 += sm[768 + k]  * hv;
            a1 += sm[1024 + k] * hv;
            a2 += sm[1280 + k] * hv;
        }
        const int tm = m >> 4, quad = (m >> 2) & 3, r = m & 3, tn = n >> 4;
        const int ln = quad*16 + (n & 15);
        const int base = ((tm*4 + tn)*64 + ln)*4 + r;
        bfrag[(0*16*64)*4  + base] = (a0 + m2b[0]) * LOG2E;
        bfrag[(16*64)*4    + base] = (a1 + m2b[1]) * LOG2E;
        bfrag[(32*64)*4    + base] = (a2 + m2b[2]) * LOG2E;
    } else if (gid < 4096 + 6912) {
        const int idx = gid - 4096;           // ((mt*3+ks)*64 + l)*4 + j
        const int j = idx & 3, l = (idx >> 2) & 63, f = idx >> 8;
        const int ks = f % 3, mt = f / 3;
        const int row = mt*16 + (l & 15), col = ks*16 + ((l >> 4) << 2) + j;
        const float wv = (row < 96) ? qk_w[row*48 + col] : v_w[(row-96)*48 + col];
        wfrag[idx] = (_Float16)wv;
    } else if (gid < 11008 + 2304) {
        const int idx = gid - 11008;
        const int j = idx & 3, l = (idx >> 2) & 63, f = idx >> 8;
        const int ks = f % 3, mt = f / 3;
        const int row = mt*16 + (l & 15), col = ks*16 + ((l >> 4) << 2) + j;
        pfrag[idx] = (_Float16)proj_w[row*48 + col];
    } else if (gid < 13312 + 144) {
        const int c = gid - 13312;
        qkvb[c] = (c < 96) ? qk_b[c] : v_b[c - 96];
    } else if (gid < 13456 + 48) {
        pbias[gid - 13456] = proj_b[gid - 13456];
    }
}

// ---------------- fused QKV + attention + proj, fp16 MFMA -------------------
__global__ __launch_bounds__(256, 4) void win_attn_kernel(
    const float* __restrict__ X, const unsigned char* __restrict__ ws,
    float* __restrict__ out, int nblk)
{
    __shared__ _Float16 smem[12992];          // 25984 B
    _Float16* sXO = smem;                     // [64][XT_S]: X f16; later Oᵀ
    _Float16* sT  = smem + 64*XT_S;           // [64][T_S]: Q chans 0..47, K 48..95
    _Float16* sVd = smem + 64*XT_S + 64*T_S;  // [48][VD_S]: V d-major

    const float* bfrag = (const float*)(ws + WS_BFRAG);
    const f16x4* wfrag = (const f16x4*)(ws + WS_WFRAG);
    const f16x4* pfrag = (const f16x4*)(ws + WS_PFRAG);
    const float* qkvb  = (const float*)(ws + WS_QKVB);
    const float* pbias = (const float*)(ws + WS_PBIAS);

    const int tid  = threadIdx.x;
    const int wave = tid >> 6, lane = tid & 63;
    const int lq   = lane >> 4, lm = lane & 15;

    const int blk = blockIdx.x;
    const int wid = (blk & 7) * (nblk >> 3) + (blk >> 3);   // XCD swizzle
    const int batch = wid >> 12;
    const int wh = (wid >> 6) & 63, ww = wid & 63;
    const int h0 = wh << 3, w0 = ww << 3;

    const float* Xb = X + ((size_t)batch * 48 << 18);

    // ---- phase 1: stage X window -> f16 token-major LDS --------------------
    {
        const int tok = lane;
        const size_t pix = (size_t)(h0 + (tok >> 3)) * 512 + (w0 + (tok & 7));
        #pragma unroll
        for (int k = 0; k < 12; ++k) {
            const int c = wave + (k << 2);
            sXO[tok*XT_S + c] = (_Float16)Xb[((size_t)c << 18) + pix];
        }
    }
    __syncthreads();

    // ---- phase 2: QKV GEMM [144x48]x[48x64]; wave w = tokens 16w..16w+15 ---
    {
        f16x4 bx[3];
        #pragma unroll
        for (int ks = 0; ks < 3; ++ks)
            bx[ks] = *(const f16x4*)&sXO[(wave*16 + lm)*XT_S + ks*16 + lq*4];
        f16x4 aw[27];
        #pragma unroll
        for (int f = 0; f < 27; ++f) aw[f] = wfrag[f*64 + lane];

        const int tok = wave*16 + lm;
        #pragma unroll
        for (int mt = 0; mt < 9; ++mt) {
            f32x4 acc = *(const f32x4*)&qkvb[mt*16 + lq*4];
            #pragma unroll
            for (int ks = 0; ks < 3; ++ks)
                acc = __builtin_amdgcn_mfma_f32_16x16x16f16(aw[mt*3+ks], bx[ks], acc, 0, 0, 0);
            if (mt < 3) {                      // Q: fold in 0.25/sqrt-scale * log2e
                f16x4 hv;
                #pragma unroll
                for (int r = 0; r < 4; ++r) hv[r] = (_Float16)(acc[r] * (0.25f * LOG2E));
                *(f16x4*)&sT[tok*T_S + mt*16 + lq*4] = hv;
            } else if (mt < 6) {               // K
                f16x4 hv;
                #pragma unroll
                for (int r = 0; r < 4; ++r) hv[r] = (_Float16)acc[r];
                *(f16x4*)&sT[tok*T_S + mt*16 + lq*4] = hv;
            } else {                           // V -> d-major scatter
                #pragma unroll
                for (int r = 0; r < 4; ++r)
                    sVd[((mt-6)*16 + lq*4 + r)*VD_S + tok] = (_Float16)acc[r];
            }
        }
    }
    __syncthreads();

    // ---- phase 3: attention (wave = head). Sᵀ = K·Qᵀ; P stays in regs ------
    if (wave < 3) {
        const int h = wave;
        f16x4 ak[4], bq[4];
        #pragma unroll
        for (int t = 0; t < 4; ++t) {
            ak[t] = *(const f16x4*)&sT[(t*16 + lm)*T_S + 48 + h*16 + lq*4]; // K rows
            bq[t] = *(const f16x4*)&sT[(t*16 + lm)*T_S + h*16 + lq*4];     // Qᵀ cols
        }
        f32x4 s[4][4];                          // Sᵀ tiles [tm][tn], C = bias
        const f32x4* bf = (const f32x4*)bfrag + (size_t)h*16*64;
        #pragma unroll
        for (int tm = 0; tm < 4; ++tm)
            #pragma unroll
            for (int tn = 0; tn < 4; ++tn) {
                f32x4 c = bf[(tm*4 + tn)*64 + lane];
                s[tm][tn] = __builtin_amdgcn_mfma_f32_16x16x16f16(ak[tm], bq[tn], c, 0, 0, 0);
            }
        // softmax over m (rows of Sᵀ): no-max exp2 (bounded logits, log2e
        // pre-folded), in-lane sum + 2 shfls, rcp for 1/sum
        float rinv[4];
        #pragma unroll
        for (int tn = 0; tn < 4; ++tn) {
            float sum = 0.f;
            #pragma unroll
            for (int tm = 0; tm < 4; ++tm)
                #pragma unroll
                for (int r = 0; r < 4; ++r) {
                    float e = __builtin_amdgcn_exp2f(s[tm][tn][r]);
                    s[tm][tn][r] = e; sum += e;
                }
            sum += __shfl_xor(sum, 16);
            sum += __shfl_xor(sum, 32);
            rinv[tn] = __builtin_amdgcn_rcpf(sum);
        }
        // PV: Oᵀ = Vᵀ · Pᵀ ; Pᵀ C-regs are directly valid B-fragments
        f16x4 av[4];
        #pragma unroll
        for (int tm = 0; tm < 4; ++tm)
            av[tm] = *(const f16x4*)&sVd[(h*16 + lm)*VD_S + tm*16 + lq*4];
        #pragma unroll
        for (int tn = 0; tn < 4; ++tn) {
            f32x4 o = {0.f, 0.f, 0.f, 0.f};
            #pragma unroll
            for (int tm = 0; tm < 4; ++tm) {
                f16x4 pf;
                pf[0] = (_Float16)s[tm][tn][0];
                pf[1] = (_Float16)s[tm][tn][1];
                pf[2] = (_Float16)s[tm][tn][2];
                pf[3] = (_Float16)s[tm][tn][3];
                o = __builtin_amdgcn_mfma_f32_16x16x16f16(av[tm], pf, o, 0, 0, 0);
            }
            f16x4 hv;
            #pragma unroll
            for (int r = 0; r < 4; ++r) hv[r] = (_Float16)(o[r] * rinv[tn]);
            *(f16x4*)&sXO[(tn*16 + lm)*XT_S + h*16 + lq*4] = hv;   // Oᵀ rows=tok
        }
    }
    __syncthreads();

    // ---- phase 4: proj [48x48]x[48x64]; wave w = tokens 16w..16w+15 --------
    {
        f16x4 bo[3];
        #pragma unroll
        for (int ks = 0; ks < 3; ++ks)
            bo[ks] = *(const f16x4*)&sXO[(wave*16 + lm)*XT_S + ks*16 + lq*4];
        f16x4 ap[9];
        #pragma unroll
        for (int f = 0; f < 9; ++f) ap[f] = pfrag[f*64 + lane];

        const int tok = wave*16 + lm;
        float* ob = out + ((size_t)batch * 48 << 18);
        const size_t pix = (size_t)(h0 + (tok >> 3)) * 512 + (w0 + (tok & 7));
        #pragma unroll
        for (int mt = 0; mt < 3; ++mt) {
            f32x4 acc = *(const f32x4*)&pbias[mt*16 + lq*4];
            #pragma unroll
            for (int ks = 0; ks < 3; ++ks)
                acc = __builtin_amdgcn_mfma_f32_16x16x16f16(ap[mt*3+ks], bo[ks], acc, 0, 0, 0);
            #pragma unroll
            for (int r = 0; r < 4; ++r)
                ob[((size_t)(mt*16 + lq*4 + r) << 18) + pix] = acc[r];
        }
    }
}

extern "C" void kernel_launch(void* const* d_in, const int* in_sizes, int n_in,
                              void* d_out, int out_size, void* d_ws, size_t ws_size,
                              hipStream_t stream) {
    (void)n_in; (void)out_size; (void)ws_size;
    const float* X      = (const float*)d_in[0];
    const float* v_w    = (const float*)d_in[1];
    const float* v_b    = (const float*)d_in[2];
    const float* qk_w   = (const float*)d_in[3];
    const float* qk_b   = (const float*)d_in[4];
    const float* proj_w = (const float*)d_in[5];
    const float* proj_b = (const float*)d_in[6];
    const float* m1w    = (const float*)d_in[7];
    const float* m1b    = (const float*)d_in[8];
    const float* m2w    = (const float*)d_in[9];
    const float* m2b    = (const float*)d_in[10];
    float* out = (float*)d_out;
    unsigned char* ws = (unsigned char*)d_ws;   // ~68.4 KB used

    const int B = in_sizes[0] / (48 * 512 * 512);   // = 2
    const int nblk = B * 64 * 64;

    hipLaunchKernelGGL(prep_kernel, dim3(53), dim3(256), 0, stream,
                       m1w, m1b, m2w, m2b, qk_w, v_w, proj_w, qk_b, v_b, proj_b, ws);
    hipLaunchKernelGGL(win_attn_kernel, dim3(nblk), dim3(256), 0, stream,
                       X, ws, out, nblk);
}